// Round 13
// baseline (131.679 us; speedup 1.0000x reference)
//
#include <hip/hip_runtime.h>
#include <hip/hip_bf16.h>
#include <math.h>

#define T_TOK   1024
#define D_DIM   1024
#define E_NUM   8
#define F_DIM   768
#define N_SLOTS 2048

typedef unsigned short u16;
typedef unsigned int   u32;
typedef __attribute__((ext_vector_type(8))) short bf16x8;
typedef __attribute__((ext_vector_type(4))) float f32x4;

// ---- workspace layout (byte offsets) ----
#define WS_SEL    0
#define WS_WTS    8192
#define WS_BUCKET 16384
#define WS_COUNTS 49152
#define WS_OFFS   49216
#define WS_POS    49280
#define WS_XB     65536                    // bf16[1024][1024]  2 MB
#define WS_H      (WS_XB + 2097152)        // bf16[3072][768]   4.7 MB
#define WS_Y      (WS_H + 4718592)         // f32 [3072][1024]  12.6 MB

__device__ __forceinline__ u16 f2bf(float x) {            // RNE
    u32 u = __float_as_uint(x);
    u += 0x7fffu + ((u >> 16) & 1u);
    return (u16)(u >> 16);
}
// pack 2 fp32 -> 2 bf16 (truncate) in one v_perm_b32: result = [hi.bf16 | lo.bf16]
#define PKBF(hi, lo) __builtin_amdgcn_perm(__float_as_uint(hi), __float_as_uint(lo), 0x07060302u)

// 64-u16 LDS rows (128B, 8 chunks of 8 u16); chunk swizzle phys = c ^ (row&7).
// Proven near-zero-conflict (round 10).
__device__ __forceinline__ int physB(int r, int c) {
    return r * 64 + ((c ^ (r & 7)) << 3);
}

// async global->LDS, 16B/lane; LDS dest = wave-uniform base + lane*16 (linear).
// Swizzle achieved by pre-swizzling the per-lane GLOBAL source chunk.
__device__ __forceinline__ void async16(const void* gp, void* sp) {
    __builtin_amdgcn_global_load_lds(
        (const __attribute__((address_space(1))) unsigned int*)gp,
        (__attribute__((address_space(3))) unsigned int*)sp, 16, 0, 0);
}

// ---------------- xrouter: bf16-convert X row + router top-2 ----------------
__global__ __launch_bounds__(256) void xrouter_kernel(
    const float* __restrict__ X, const float* __restrict__ Wr,
    const float* __restrict__ bias, u16* __restrict__ Xb,
    int* __restrict__ sel, float* __restrict__ wts)
{
    int t = blockIdx.x * 4 + (threadIdx.x >> 6);
    int lane = threadIdx.x & 63;
    const float* xrow = X + (size_t)t * D_DIM;
    u16* brow = Xb + (size_t)t * D_DIM;
    float acc[E_NUM];
#pragma unroll
    for (int e = 0; e < E_NUM; ++e) acc[e] = 0.f;
#pragma unroll
    for (int q = 0; q < 4; ++q) {
        int d = q * 256 + lane * 4;
        float4 v = *(const float4*)(xrow + d);
        ushort4 o;
        o.x = f2bf(v.x); o.y = f2bf(v.y); o.z = f2bf(v.z); o.w = f2bf(v.w);
        *(ushort4*)(brow + d) = o;
        const float xv[4] = {v.x, v.y, v.z, v.w};
#pragma unroll
        for (int jj = 0; jj < 4; ++jj) {
            const float4* wr = (const float4*)(Wr + (size_t)(d + jj) * E_NUM);
            float4 w0 = wr[0], w1 = wr[1];
            acc[0] += xv[jj] * w0.x; acc[1] += xv[jj] * w0.y;
            acc[2] += xv[jj] * w0.z; acc[3] += xv[jj] * w0.w;
            acc[4] += xv[jj] * w1.x; acc[5] += xv[jj] * w1.y;
            acc[6] += xv[jj] * w1.z; acc[7] += xv[jj] * w1.w;
        }
    }
#pragma unroll
    for (int e = 0; e < E_NUM; ++e)
#pragma unroll
        for (int off = 32; off > 0; off >>= 1)
            acc[e] += __shfl_xor(acc[e], off);
    if (lane == 0) {
        float s[E_NUM], b[E_NUM];
#pragma unroll
        for (int e = 0; e < E_NUM; ++e) {
            s[e] = 1.f / (1.f + expf(-acc[e]));
            b[e] = s[e] + bias[e];
        }
        int i1 = 0; float b1 = b[0];
#pragma unroll
        for (int e = 1; e < E_NUM; ++e) if (b[e] > b1) { b1 = b[e]; i1 = e; }
        int i2 = -1; float b2 = -INFINITY;
#pragma unroll
        for (int e = 0; e < E_NUM; ++e) {
            if (e == i1) continue;
            if (b[e] > b2) { b2 = b[e]; i2 = e; }
        }
        float s1 = s[i1], s2 = s[i2];
        float denom = s1 + s2 + 1e-20f;
        sel[2 * t] = i1; sel[2 * t + 1] = i2;
        wts[2 * t] = s1 / denom; wts[2 * t + 1] = s2 / denom;
    }
}

// ---------------- dispatch ----------------
__global__ __launch_bounds__(512) void dispatch_kernel(
    const int* __restrict__ sel, int* __restrict__ bucket,
    int* __restrict__ counts, int* __restrict__ offs, int* __restrict__ pos)
{
    __shared__ int soffs[E_NUM + 1];
    int e = threadIdx.x >> 6;
    int lane = threadIdx.x & 63;
    int running = 0;
    for (int base = 0; base < N_SLOTS; base += 64) {
        int slot = base + lane;
        bool mine = (sel[slot] == e);
        unsigned long long mask = __ballot(mine);
        if (mine) {
            int rank = running + __popcll(mask & ((1ull << lane) - 1ull));
            bucket[e * T_TOK + rank] = slot;
        }
        running += __popcll(mask);
    }
    if (lane == 0) counts[e] = running;
    __syncthreads();
    if (threadIdx.x == 0) {
        int o = 0;
        for (int k = 0; k < E_NUM; ++k) { soffs[k] = o; offs[k] = o; o += counts[k]; }
        soffs[E_NUM] = o; offs[E_NUM] = o;
    }
    __syncthreads();
    int base_off = soffs[e];
    for (int r = lane; r < running; r += 64)
        pos[bucket[e * T_TOK + r]] = base_off + r;
}

// ================= proj1 (FLIPPED): D[m=f][n=token], weights read ONCE =================
// A = W columns (32 gate f + 32 up f per panel), B = 256 token rows (async16, cache-hot).
// BK=64, 16 K-steps. LDS rows: 0..63 A (gate 0..31, up 32..63), 64..319 B tokens. 80 KB.
// grid 864: unit = i/96; panel x = (i%96)>>2 (32 F-cols); nt = i&3 (256-token tile).
__global__ __launch_bounds__(256, 2) void proj1(
    const u16* __restrict__ Xb,
    const float* __restrict__ Wg, const float* __restrict__ Wu,
    const float* __restrict__ Wgs, const float* __restrict__ Wus,
    u16* __restrict__ H,
    const int* __restrict__ bucket, const int* __restrict__ counts,
    const int* __restrict__ offs)
{
    const int i = blockIdx.x;
    const int unit = i / 96;
    const int rem = i - unit * 96;
    const int x = rem >> 2;
    const int nt = rem & 3;

    int nrows, rbase; const float *Bg, *Bu;
    if (unit < E_NUM) {
        nrows = counts[unit]; rbase = offs[unit];
        Bg = Wg + (size_t)unit * D_DIM * F_DIM;
        Bu = Wu + (size_t)unit * D_DIM * F_DIM;
    } else { nrows = T_TOK; rbase = N_SLOTS; Bg = Wgs; Bu = Wus; }
    const int tbase = nt * 256;
    if (tbase >= nrows) return;

    __shared__ u16 smem[2][320 * 64];

    const int t = threadIdx.x, wv = t >> 6, lane = t & 63, l15 = lane & 15, g = lane >> 4;

    // ---- A staging: thread -> W column m=lane (0..31 gate, 32..63 up), k-quarter wv ----
    const float* srcA = ((lane < 32) ? Bg : Bu) + (size_t)(wv * 16) * F_DIM + x * 32 + (lane & 31);
    const int wA0 = physB(lane, 2 * wv);
    const int wA1 = physB(lane, 2 * wv + 1);

    // ---- B staging: 8 async16/thread; lane -> (row8 = lane>>3, chunk = lane&7) ----
    const u16* srcB[8];
#pragma unroll
    for (int j = 0; j < 8; ++j) {
        int tl = wv * 64 + j * 8 + (lane >> 3);
        int tok = min(tbase + tl, nrows - 1);
        int grow = (unit < E_NUM) ? (bucket[unit * T_TOK + tok] >> 1) : tok;
        srcB[j] = Xb + (size_t)grow * D_DIM + (((lane & 7) ^ (lane >> 3)) << 3);
    }

    f32x4 accg[2][4], accu[2][4];
    const f32x4 z4 = {0.f, 0.f, 0.f, 0.f};
#pragma unroll
    for (int mi = 0; mi < 2; ++mi)
#pragma unroll
        for (int ni = 0; ni < 4; ++ni) { accg[mi][ni] = z4; accu[mi][ni] = z4; }

    float pa[16];
#define ASYNCB1(kt, buf) do { \
    _Pragma("unroll") \
    for (int j = 0; j < 8; ++j) \
        async16(srcB[j] + (kt), &smem[buf][(64 + wv * 64 + j * 8) * 64]); \
} while (0)
#define LOADA1(kt) do { \
    const float* _s = srcA + (size_t)(kt) * F_DIM; \
    _Pragma("unroll") \
    for (int j = 0; j < 16; ++j) pa[j] = _s[(size_t)j * F_DIM]; \
} while (0)
#define WRITEA1(buf) do { \
    u32 pk[8]; \
    _Pragma("unroll") \
    for (int j = 0; j < 8; ++j) pk[j] = PKBF(pa[2*j + 1], pa[2*j]); \
    *(uint4*)&smem[buf][wA0] = *(const uint4*)&pk[0]; \
    *(uint4*)&smem[buf][wA1] = *(const uint4*)&pk[4]; \
} while (0)
#define COMP1(buf) do { \
    const u16* _p = smem[buf]; \
    _Pragma("unroll") \
    for (int kk = 0; kk < 2; ++kk) { \
        const int ch = (((kk << 2) | g) ^ (l15 & 7)) << 3; \
        bf16x8 _ag[2], _au[2], _b[4]; \
        _Pragma("unroll") \
        for (int mi = 0; mi < 2; ++mi) { \
            _ag[mi] = *(const bf16x8*)&_p[(mi * 16 + l15) * 64 + ch]; \
            _au[mi] = *(const bf16x8*)&_p[(32 + mi * 16 + l15) * 64 + ch]; \
        } \
        _Pragma("unroll") \
        for (int ni = 0; ni < 4; ++ni) \
            _b[ni] = *(const bf16x8*)&_p[(64 + wv * 64 + ni * 16 + l15) * 64 + ch]; \
        _Pragma("unroll") \
        for (int mi = 0; mi < 2; ++mi) \
            _Pragma("unroll") \
            for (int ni = 0; ni < 4; ++ni) { \
                accg[mi][ni] = __builtin_amdgcn_mfma_f32_16x16x32_bf16(_ag[mi], _b[ni], accg[mi][ni], 0, 0, 0); \
                accu[mi][ni] = __builtin_amdgcn_mfma_f32_16x16x32_bf16(_au[mi], _b[ni], accu[mi][ni], 0, 0, 0); \
            } \
    } \
} while (0)

    ASYNCB1(0, 0);
    LOADA1(0);
    WRITEA1(0);
    __syncthreads();
    for (int tt = 0; tt < 16; ++tt) {
        const int cb = tt & 1, nb = cb ^ 1;
        if (tt + 1 < 16) { ASYNCB1((tt + 1) * 64, nb); LOADA1((tt + 1) * 64); }
        COMP1(cb);
        if (tt + 1 < 16) WRITEA1(nb);
        __syncthreads();
    }
#undef ASYNCB1
#undef LOADA1
#undef WRITEA1
#undef COMP1

    // epilogue: lane holds gate&up for token = tbase+wv*64+ni*16+l15, f = x*32+mi*16+g*4+r
#pragma unroll
    for (int mi = 0; mi < 2; ++mi)
#pragma unroll
        for (int ni = 0; ni < 4; ++ni) {
            int token = tbase + wv * 64 + ni * 16 + l15;
            if (token >= nrows) continue;
            int f0 = x * 32 + mi * 16 + g * 4;
            ushort4 hv;
            float gv, uv;
            gv = accg[mi][ni][0]; uv = accu[mi][ni][0];
            hv.x = f2bf(gv / (1.f + __expf(-gv)) * uv);
            gv = accg[mi][ni][1]; uv = accu[mi][ni][1];
            hv.y = f2bf(gv / (1.f + __expf(-gv)) * uv);
            gv = accg[mi][ni][2]; uv = accu[mi][ni][2];
            hv.z = f2bf(gv / (1.f + __expf(-gv)) * uv);
            gv = accg[mi][ni][3]; uv = accu[mi][ni][3];
            hv.w = f2bf(gv / (1.f + __expf(-gv)) * uv);
            *(ushort4*)(H + (size_t)(rbase + token) * F_DIM + f0) = hv;
        }
}

// ================= proj2 (FLIPPED): D[m=d][n=token], Wd read ONCE =================
// A = Wd columns (64 d per panel), B = 256 H rows (async16, cache-hot). BK=64, 12 steps.
// LDS rows: 0..63 A, 64..319 B. grid 576: unit=i/64; x=(i%64)>>2 (64 d-cols); nt=i&3.
__global__ __launch_bounds__(256, 2) void proj2(
    const u16* __restrict__ H,
    const float* __restrict__ Wd, const float* __restrict__ Wds,
    float* __restrict__ Y,
    const int* __restrict__ counts, const int* __restrict__ offs)
{
    const int i = blockIdx.x;
    const int unit = i / 64;
    const int rem = i - unit * 64;
    const int x = rem >> 2;
    const int nt = rem & 3;

    int nrows, rbase; const float* Bm;
    if (unit < E_NUM) {
        nrows = counts[unit]; rbase = offs[unit];
        Bm = Wd + (size_t)unit * F_DIM * D_DIM;
    } else { nrows = T_TOK; rbase = N_SLOTS; Bm = Wds; }
    const int tbase = nt * 256;
    if (tbase >= nrows) return;

    __shared__ u16 smem[2][320 * 64];

    const int t = threadIdx.x, wv = t >> 6, lane = t & 63, l15 = lane & 15, g = lane >> 4;

    // A: thread -> Wd column d = x*64+lane, k-quarter wv (16 f's, stride D_DIM)
    const float* srcA = Bm + (size_t)(wv * 16) * D_DIM + x * 64 + lane;
    const int wA0 = physB(lane, 2 * wv);
    const int wA1 = physB(lane, 2 * wv + 1);

    // B: H token rows via async16
    const u16* srcB[8];
#pragma unroll
    for (int j = 0; j < 8; ++j) {
        int tl = wv * 64 + j * 8 + (lane >> 3);
        int tok = min(tbase + tl, nrows - 1);
        srcB[j] = H + (size_t)(rbase + tok) * F_DIM + (((lane & 7) ^ (lane >> 3)) << 3);
    }

    f32x4 acc[4][4];
    const f32x4 z4 = {0.f, 0.f, 0.f, 0.f};
#pragma unroll
    for (int mi = 0; mi < 4; ++mi)
#pragma unroll
        for (int ni = 0; ni < 4; ++ni) acc[mi][ni] = z4;

    float pa[16];
#define ASYNCB2(kt, buf) do { \
    _Pragma("unroll") \
    for (int j = 0; j < 8; ++j) \
        async16(srcB[j] + (kt), &smem[buf][(64 + wv * 64 + j * 8) * 64]); \
} while (0)
#define LOADA2(kt) do { \
    const float* _s = srcA + (size_t)(kt) * D_DIM; \
    _Pragma("unroll") \
    for (int j = 0; j < 16; ++j) pa[j] = _s[(size_t)j * D_DIM]; \
} while (0)
#define WRITEA2(buf) do { \
    u32 pk[8]; \
    _Pragma("unroll") \
    for (int j = 0; j < 8; ++j) pk[j] = PKBF(pa[2*j + 1], pa[2*j]); \
    *(uint4*)&smem[buf][wA0] = *(const uint4*)&pk[0]; \
    *(uint4*)&smem[buf][wA1] = *(const uint4*)&pk[4]; \
} while (0)
#define COMP2(buf) do { \
    const u16* _p = smem[buf]; \
    _Pragma("unroll") \
    for (int kk = 0; kk < 2; ++kk) { \
        const int ch = (((kk << 2) | g) ^ (l15 & 7)) << 3; \
        bf16x8 _a[4], _b[4]; \
        _Pragma("unroll") \
        for (int mi = 0; mi < 4; ++mi) \
            _a[mi] = *(const bf16x8*)&_p[(mi * 16 + l15) * 64 + ch]; \
        _Pragma("unroll") \
        for (int ni = 0; ni < 4; ++ni) \
            _b[ni] = *(const bf16x8*)&_p[(64 + wv * 64 + ni * 16 + l15) * 64 + ch]; \
        _Pragma("unroll") \
        for (int mi = 0; mi < 4; ++mi) \
            _Pragma("unroll") \
            for (int ni = 0; ni < 4; ++ni) \
                acc[mi][ni] = __builtin_amdgcn_mfma_f32_16x16x32_bf16(_a[mi], _b[ni], acc[mi][ni], 0, 0, 0); \
    } \
} while (0)

    ASYNCB2(0, 0);
    LOADA2(0);
    WRITEA2(0);
    __syncthreads();
    for (int tt = 0; tt < 12; ++tt) {
        const int cb = tt & 1, nb = cb ^ 1;
        if (tt + 1 < 12) { ASYNCB2((tt + 1) * 64, nb); LOADA2((tt + 1) * 64); }
        COMP2(cb);
        if (tt + 1 < 12) WRITEA2(nb);
        __syncthreads();
    }
#undef ASYNCB2
#undef LOADA2
#undef WRITEA2
#undef COMP2

    // epilogue: Y[token][d0..d0+3] = acc (float4)
#pragma unroll
    for (int mi = 0; mi < 4; ++mi)
#pragma unroll
        for (int ni = 0; ni < 4; ++ni) {
            int token = tbase + wv * 64 + ni * 16 + l15;
            if (token >= nrows) continue;
            int d0 = x * 64 + mi * 16 + g * 4;
            *(f32x4*)(Y + (size_t)(rbase + token) * D_DIM + d0) = acc[mi][ni];
        }
}

// ---------------- combine ----------------
__global__ __launch_bounds__(256) void combine_kernel(
    const float* __restrict__ Y, const int* __restrict__ pos,
    const float* __restrict__ wts, float* __restrict__ out)
{
    int t = blockIdx.x;
    int d = threadIdx.x * 4;
    int p0 = pos[2 * t], p1 = pos[2 * t + 1];
    float w0 = wts[2 * t], w1 = wts[2 * t + 1];
    float4 a = *(const float4*)(Y + (size_t)(N_SLOTS + t) * D_DIM + d);
    float4 b = *(const float4*)(Y + (size_t)p0 * D_DIM + d);
    float4 cc = *(const float4*)(Y + (size_t)p1 * D_DIM + d);
    float4 o;
    o.x = a.x + w0 * b.x + w1 * cc.x;
    o.y = a.y + w0 * b.y + w1 * cc.y;
    o.z = a.z + w0 * b.z + w1 * cc.z;
    o.w = a.w + w0 * b.w + w1 * cc.w;
    *(float4*)(out + (size_t)t * D_DIM + d) = o;
}

extern "C" void kernel_launch(void* const* d_in, const int* in_sizes, int n_in,
                              void* d_out, int out_size, void* d_ws, size_t ws_size,
                              hipStream_t stream) {
    const float* X    = (const float*)d_in[0];
    const float* Wr   = (const float*)d_in[1];
    const float* bias = (const float*)d_in[2];
    const float* Wg   = (const float*)d_in[3];
    const float* Wu   = (const float*)d_in[4];
    const float* Wd   = (const float*)d_in[5];
    const float* Wgs  = (const float*)d_in[6];
    const float* Wus  = (const float*)d_in[7];
    const float* Wds  = (const float*)d_in[8];
    float* out = (float*)d_out;

    char* ws = (char*)d_ws;
    int*   sel    = (int*)(ws + WS_SEL);
    float* wtsv   = (float*)(ws + WS_WTS);
    int*   bucket = (int*)(ws + WS_BUCKET);
    int*   counts = (int*)(ws + WS_COUNTS);
    int*   offs   = (int*)(ws + WS_OFFS);
    int*   pos    = (int*)(ws + WS_POS);
    u16*   Xb     = (u16*)(ws + WS_XB);
    u16*   H      = (u16*)(ws + WS_H);
    float* Y      = (float*)(ws + WS_Y);

    xrouter_kernel<<<256, 256, 0, stream>>>(X, Wr, bias, Xb, sel, wtsv);
    dispatch_kernel<<<1, 512, 0, stream>>>(sel, bucket, counts, offs, pos);

    proj1<<<864, 256, 0, stream>>>(Xb, Wg, Wu, Wgs, Wus, H, bucket, counts, offs);
    proj2<<<576, 256, 0, stream>>>(H, Wd, Wds, Y, counts, offs);
    combine_kernel<<<T_TOK, 256, 0, stream>>>(Y, pos, wtsv, out);
}

// Round 14
// 87.550 us; speedup vs baseline: 1.5041x; 1.5041x over previous
//
#include <hip/hip_runtime.h>
#include <hip/hip_bf16.h>
#include <math.h>

#define T_TOK   1024
#define D_DIM   1024
#define E_NUM   8
#define F_DIM   768
#define N_SLOTS 2048

typedef unsigned short u16;
typedef unsigned int   u32;
typedef __attribute__((ext_vector_type(8))) short bf16x8;
typedef __attribute__((ext_vector_type(4))) float f32x4;

// ---- workspace layout (byte offsets) ----
#define WS_SEL    0
#define WS_WTS    8192
#define WS_BUCKET 16384
#define WS_COUNTS 49152
#define WS_OFFS   49216
#define WS_POS    49280
#define WS_XB     65536                    // bf16[1024][1024]  2 MB
#define WS_H      (WS_XB + 2097152)        // bf16[3072][768]   4.7 MB
#define WS_Y      (WS_H + 4718592)         // f32 [3072][1024]  12.6 MB

__device__ __forceinline__ u16 f2bf(float x) {            // RNE
    u32 u = __float_as_uint(x);
    u += 0x7fffu + ((u >> 16) & 1u);
    return (u16)(u >> 16);
}
// pack 2 fp32 -> 2 bf16 (truncate) in one v_perm_b32: result = [hi.bf16 | lo.bf16]
#define PKBF(hi, lo) __builtin_amdgcn_perm(__float_as_uint(hi), __float_as_uint(lo), 0x07060302u)

// ---------------- xrouter: bf16-convert X row + router top-2 ----------------
__global__ __launch_bounds__(256) void xrouter_kernel(
    const float* __restrict__ X, const float* __restrict__ Wr,
    const float* __restrict__ bias, u16* __restrict__ Xb,
    int* __restrict__ sel, float* __restrict__ wts)
{
    int t = blockIdx.x * 4 + (threadIdx.x >> 6);
    int lane = threadIdx.x & 63;
    const float* xrow = X + (size_t)t * D_DIM;
    u16* brow = Xb + (size_t)t * D_DIM;
    float acc[E_NUM];
#pragma unroll
    for (int e = 0; e < E_NUM; ++e) acc[e] = 0.f;
#pragma unroll
    for (int q = 0; q < 4; ++q) {
        int d = q * 256 + lane * 4;
        float4 v = *(const float4*)(xrow + d);
        ushort4 o;
        o.x = f2bf(v.x); o.y = f2bf(v.y); o.z = f2bf(v.z); o.w = f2bf(v.w);
        *(ushort4*)(brow + d) = o;
        const float xv[4] = {v.x, v.y, v.z, v.w};
#pragma unroll
        for (int jj = 0; jj < 4; ++jj) {
            const float4* wr = (const float4*)(Wr + (size_t)(d + jj) * E_NUM);
            float4 w0 = wr[0], w1 = wr[1];
            acc[0] += xv[jj] * w0.x; acc[1] += xv[jj] * w0.y;
            acc[2] += xv[jj] * w0.z; acc[3] += xv[jj] * w0.w;
            acc[4] += xv[jj] * w1.x; acc[5] += xv[jj] * w1.y;
            acc[6] += xv[jj] * w1.z; acc[7] += xv[jj] * w1.w;
        }
    }
#pragma unroll
    for (int e = 0; e < E_NUM; ++e)
#pragma unroll
        for (int off = 32; off > 0; off >>= 1)
            acc[e] += __shfl_xor(acc[e], off);
    if (lane == 0) {
        float s[E_NUM], b[E_NUM];
#pragma unroll
        for (int e = 0; e < E_NUM; ++e) {
            s[e] = 1.f / (1.f + expf(-acc[e]));
            b[e] = s[e] + bias[e];
        }
        int i1 = 0; float b1 = b[0];
#pragma unroll
        for (int e = 1; e < E_NUM; ++e) if (b[e] > b1) { b1 = b[e]; i1 = e; }
        int i2 = -1; float b2 = -INFINITY;
#pragma unroll
        for (int e = 0; e < E_NUM; ++e) {
            if (e == i1) continue;
            if (b[e] > b2) { b2 = b[e]; i2 = e; }
        }
        float s1 = s[i1], s2 = s[i2];
        float denom = s1 + s2 + 1e-20f;
        sel[2 * t] = i1; sel[2 * t + 1] = i2;
        wts[2 * t] = s1 / denom; wts[2 * t + 1] = s2 / denom;
    }
}

// ---------------- dispatch ----------------
__global__ __launch_bounds__(512) void dispatch_kernel(
    const int* __restrict__ sel, int* __restrict__ bucket,
    int* __restrict__ counts, int* __restrict__ offs, int* __restrict__ pos)
{
    __shared__ int soffs[E_NUM + 1];
    int e = threadIdx.x >> 6;
    int lane = threadIdx.x & 63;
    int running = 0;
    for (int base = 0; base < N_SLOTS; base += 64) {
        int slot = base + lane;
        bool mine = (sel[slot] == e);
        unsigned long long mask = __ballot(mine);
        if (mine) {
            int rank = running + __popcll(mask & ((1ull << lane) - 1ull));
            bucket[e * T_TOK + rank] = slot;
        }
        running += __popcll(mask);
    }
    if (lane == 0) counts[e] = running;
    __syncthreads();
    if (threadIdx.x == 0) {
        int o = 0;
        for (int k = 0; k < E_NUM; ++k) { soffs[k] = o; offs[k] = o; o += counts[k]; }
        soffs[E_NUM] = o; offs[E_NUM] = o;
    }
    __syncthreads();
    int base_off = soffs[e];
    for (int r = lane; r < running; r += 64)
        pos[bucket[e * T_TOK + r]] = base_off + r;
}

// ================= proj1: H = silu(Xb@Wg) * (Xb@Wu), fp32 weights read directly =================
// BM=64, BN=128 virtual (gate64+up64), BK=64, 16 K-steps, 2-deep reg pipeline (counted vmcnt).
// LDS rows of 64 u16 (128B, 8 chunks), chunk swizzle phys = c ^ (row&7) (round-10, 627K conflicts).
// grid 1792: cxcd=i&7, m=i>>3, y=m&15, phi=m>>4; panel=phi*8+cxcd (<108); unit=panel/12, x=panel%12
__global__ __launch_bounds__(256, 3) void proj1(
    const u16* __restrict__ Xb,
    const float* __restrict__ Wg, const float* __restrict__ Wu,
    const float* __restrict__ Wgs, const float* __restrict__ Wus,
    u16* __restrict__ H,
    const int* __restrict__ bucket, const int* __restrict__ counts, const int* __restrict__ offs)
{
    const int i = blockIdx.x;
    const int cxcd = i & 7, m = i >> 3;
    const int y = m & 15, phi = m >> 4;
    const int panel = phi * 8 + cxcd;
    if (panel >= 108) return;
    const int unit = panel / 12, x = panel - unit * 12;

    int nrows, rbase; const float *Bg, *Bu;
    if (unit < E_NUM) {
        nrows = counts[unit]; rbase = offs[unit];
        Bg = Wg + (size_t)unit * D_DIM * F_DIM;
        Bu = Wu + (size_t)unit * D_DIM * F_DIM;
    } else { nrows = T_TOK; rbase = N_SLOTS; Bg = Wgs; Bu = Wus; }
    const int row0 = y * 64;
    if (row0 >= nrows) return;

    // rows 0..63 = A, 64..127 = gate B, 128..191 = up B; each row 64 u16 (8 chunks)
    __shared__ u16 smem[2][192 * 64];

    const int t = threadIdx.x;
    const int wv = t >> 6, lane = t & 63, l15 = lane & 15, g = lane >> 4;
    const int wm = wv >> 1, wn = wv & 1;

    // ---- A staging: thread -> (row = t>>2, chunks c0 = t&3 and c0+4) ----
    const int ar = t >> 2, ac = t & 3;
    int grow = min(row0 + ar, nrows - 1);
    if (unit < E_NUM) grow = bucket[unit * T_TOK + grow] >> 1;
    const u16* srcA = Xb + (size_t)grow * D_DIM + ac * 8;
    const int wA0 = ar * 64 + ((ac     ^ (ar & 7)) * 8);
    const int wA1 = ar * 64 + (((ac+4) ^ (ar & 7)) * 8);

    // ---- B staging: thread -> vrow bn (0..127), k-half bh (32 k each) ----
    const int bn = (t & 63) | (((t >> 6) & 1) << 6);
    const int bh = t >> 7;
    const float* srcB = ((bn < 64) ? Bg : Bu) + (size_t)(bh * 32) * F_DIM + x * 64 + (bn & 63);
    int wB[4];
#pragma unroll
    for (int q = 0; q < 4; ++q)
        wB[q] = (64 + bn) * 64 + (((bh * 4 + q) ^ (bn & 7)) * 8);

    f32x4 accg[2][2], accu[2][2];
    const f32x4 z4 = {0.f, 0.f, 0.f, 0.f};
#pragma unroll
    for (int ri = 0; ri < 2; ++ri)
#pragma unroll
        for (int ci = 0; ci < 2; ++ci) { accg[ri][ci] = z4; accu[ri][ci] = z4; }

    // 2-deep register pipeline slots
    uint4 a0A, a1A, a0B, a1B;
    float pbA[32], pbB[32];
#define LOAD1A(kt) do { \
    a0A = *(const uint4*)(srcA + (kt)); \
    a1A = *(const uint4*)(srcA + (kt) + 32); \
    const float* _bp = srcB + (size_t)(kt) * F_DIM; \
    _Pragma("unroll") \
    for (int ii = 0; ii < 32; ++ii) pbA[ii] = _bp[(size_t)ii * F_DIM]; \
} while (0)
#define LOAD1B(kt) do { \
    a0B = *(const uint4*)(srcA + (kt)); \
    a1B = *(const uint4*)(srcA + (kt) + 32); \
    const float* _bp = srcB + (size_t)(kt) * F_DIM; \
    _Pragma("unroll") \
    for (int ii = 0; ii < 32; ++ii) pbB[ii] = _bp[(size_t)ii * F_DIM]; \
} while (0)
#define WRITE1(pa0, pa1, pb, buf) do { \
    *(uint4*)&smem[buf][wA0] = pa0; \
    *(uint4*)&smem[buf][wA1] = pa1; \
    _Pragma("unroll") \
    for (int q = 0; q < 4; ++q) { \
        u32 pk[4]; \
        _Pragma("unroll") \
        for (int j = 0; j < 4; ++j) pk[j] = PKBF(pb[8*q + 2*j + 1], pb[8*q + 2*j]); \
        *(uint4*)&smem[buf][wB[q]] = *(const uint4*)pk; \
    } \
} while (0)
#define COMP1(buf) do { \
    const u16* _p = smem[buf]; \
    _Pragma("unroll") \
    for (int kk = 0; kk < 2; ++kk) { \
        const int ch = (((kk << 2) | g) ^ (l15 & 7)) * 8; \
        bf16x8 _a[2], _bg[2], _bu[2]; \
        _Pragma("unroll") \
        for (int ri = 0; ri < 2; ++ri) \
            _a[ri] = *(const bf16x8*)&_p[(wm * 32 + ri * 16 + l15) * 64 + ch]; \
        _Pragma("unroll") \
        for (int ci = 0; ci < 2; ++ci) { \
            _bg[ci] = *(const bf16x8*)&_p[(64  + wn * 32 + ci * 16 + l15) * 64 + ch]; \
            _bu[ci] = *(const bf16x8*)&_p[(128 + wn * 32 + ci * 16 + l15) * 64 + ch]; \
        } \
        _Pragma("unroll") \
        for (int ri = 0; ri < 2; ++ri) \
            _Pragma("unroll") \
            for (int ci = 0; ci < 2; ++ci) { \
                accg[ri][ci] = __builtin_amdgcn_mfma_f32_16x16x32_bf16(_a[ri], _bg[ci], accg[ri][ci], 0, 0, 0); \
                accu[ri][ci] = __builtin_amdgcn_mfma_f32_16x16x32_bf16(_a[ri], _bu[ci], accu[ri][ci], 0, 0, 0); \
            } \
    } \
} while (0)

    LOAD1A(0);
    LOAD1B(64);
    for (int tt = 0; tt < 16; tt += 2) {
        WRITE1(a0A, a1A, pbA, 0);
        LOAD1A(min(tt + 2, 15) * 64);
        __syncthreads();
        COMP1(0);
        WRITE1(a0B, a1B, pbB, 1);
        LOAD1B(min(tt + 3, 15) * 64);
        __syncthreads();
        COMP1(1);
    }
#undef LOAD1A
#undef LOAD1B
#undef WRITE1
#undef COMP1

    // epilogue: fused SiLU-GLU, write H bf16 (RNE)
#pragma unroll
    for (int ri = 0; ri < 2; ++ri)
#pragma unroll
        for (int ci = 0; ci < 2; ++ci) {
            int n = x * 64 + wn * 32 + ci * 16 + l15;
#pragma unroll
            for (int r = 0; r < 4; ++r) {
                int row = row0 + wm * 32 + ri * 16 + g * 4 + r;
                if (row >= nrows) continue;
                float gv = accg[ri][ci][r];
                float uv = accu[ri][ci][r];
                H[(size_t)(rbase + row) * F_DIM + n] =
                    f2bf(gv / (1.f + __expf(-gv)) * uv);
            }
        }
}

// ================= proj2: Y = H @ Wd, fp32 weights read directly =================
// BM=64, BN=64, BK=64, 12 K-steps, 2-deep reg pipeline. LDS rows 0..63 A, 64..127 B.
// grid 2304: cxcd=i&7, m=i>>3, y=m&15, phi=m>>4; panel=phi*8+cxcd (<144); unit=panel>>4, x=panel&15
__global__ __launch_bounds__(256, 3) void proj2(
    const u16* __restrict__ H,
    const float* __restrict__ Wd, const float* __restrict__ Wds,
    float* __restrict__ Y,
    const int* __restrict__ counts, const int* __restrict__ offs)
{
    const int i = blockIdx.x;
    const int cxcd = i & 7, m = i >> 3;
    const int y = m & 15, phi = m >> 4;
    const int panel = phi * 8 + cxcd;
    if (panel >= 144) return;
    const int unit = panel >> 4, x = panel & 15;

    int nrows, rbase; const float* Bm;
    if (unit < E_NUM) {
        nrows = counts[unit]; rbase = offs[unit];
        Bm = Wd + (size_t)unit * F_DIM * D_DIM;
    } else { nrows = T_TOK; rbase = N_SLOTS; Bm = Wds; }
    const int row0 = y * 64;
    if (row0 >= nrows) return;

    __shared__ u16 smem[2][128 * 64];

    const int t = threadIdx.x;
    const int wv = t >> 6, lane = t & 63, l15 = lane & 15, g = lane >> 4;
    const int wm = wv >> 1, wn = wv & 1;

    const int ar = t >> 2, ac = t & 3;
    const int grow = rbase + min(row0 + ar, nrows - 1);
    const u16* srcA = H + (size_t)grow * F_DIM + ac * 8;
    const int wA0 = ar * 64 + ((ac     ^ (ar & 7)) * 8);
    const int wA1 = ar * 64 + (((ac+4) ^ (ar & 7)) * 8);

    const int bn = t & 63;
    const int bq = t >> 6;
    const float* srcB = Bm + (size_t)(bq * 16) * D_DIM + x * 64 + bn;
    int wB[2];
#pragma unroll
    for (int q = 0; q < 2; ++q)
        wB[q] = (64 + bn) * 64 + (((bq * 2 + q) ^ (bn & 7)) * 8);

    f32x4 acc[2][2];
    const f32x4 z4 = {0.f, 0.f, 0.f, 0.f};
#pragma unroll
    for (int ri = 0; ri < 2; ++ri)
#pragma unroll
        for (int ci = 0; ci < 2; ++ci) acc[ri][ci] = z4;

    uint4 a0A, a1A, a0B, a1B;
    float pbA[16], pbB[16];
#define LOAD2A(kt) do { \
    a0A = *(const uint4*)(srcA + (kt)); \
    a1A = *(const uint4*)(srcA + (kt) + 32); \
    const float* _bp = srcB + (size_t)(kt) * D_DIM; \
    _Pragma("unroll") \
    for (int ii = 0; ii < 16; ++ii) pbA[ii] = _bp[(size_t)ii * D_DIM]; \
} while (0)
#define LOAD2B(kt) do { \
    a0B = *(const uint4*)(srcA + (kt)); \
    a1B = *(const uint4*)(srcA + (kt) + 32); \
    const float* _bp = srcB + (size_t)(kt) * D_DIM; \
    _Pragma("unroll") \
    for (int ii = 0; ii < 16; ++ii) pbB[ii] = _bp[(size_t)ii * D_DIM]; \
} while (0)
#define WRITE2(pa0, pa1, pb, buf) do { \
    *(uint4*)&smem[buf][wA0] = pa0; \
    *(uint4*)&smem[buf][wA1] = pa1; \
    _Pragma("unroll") \
    for (int q = 0; q < 2; ++q) { \
        u32 pk[4]; \
        _Pragma("unroll") \
        for (int j = 0; j < 4; ++j) pk[j] = PKBF(pb[8*q + 2*j + 1], pb[8*q + 2*j]); \
        *(uint4*)&smem[buf][wB[q]] = *(const uint4*)pk; \
    } \
} while (0)
#define COMP2(buf) do { \
    const u16* _p = smem[buf]; \
    _Pragma("unroll") \
    for (int kk = 0; kk < 2; ++kk) { \
        const int ch = (((kk << 2) | g) ^ (l15 & 7)) * 8; \
        bf16x8 _a[2], _b[2]; \
        _Pragma("unroll") \
        for (int ri = 0; ri < 2; ++ri) \
            _a[ri] = *(const bf16x8*)&_p[(wm * 32 + ri * 16 + l15) * 64 + ch]; \
        _Pragma("unroll") \
        for (int ci = 0; ci < 2; ++ci) \
            _b[ci] = *(const bf16x8*)&_p[(64 + wn * 32 + ci * 16 + l15) * 64 + ch]; \
        _Pragma("unroll") \
        for (int ri = 0; ri < 2; ++ri) \
            _Pragma("unroll") \
            for (int ci = 0; ci < 2; ++ci) \
                acc[ri][ci] = __builtin_amdgcn_mfma_f32_16x16x32_bf16(_a[ri], _b[ci], acc[ri][ci], 0, 0, 0); \
    } \
} while (0)

    LOAD2A(0);
    LOAD2B(64);
    for (int tt = 0; tt < 12; tt += 2) {
        WRITE2(a0A, a1A, pbA, 0);
        LOAD2A(min(tt + 2, 11) * 64);
        __syncthreads();
        COMP2(0);
        WRITE2(a0B, a1B, pbB, 1);
        LOAD2B(min(tt + 3, 11) * 64);
        __syncthreads();
        COMP2(1);
    }
#undef LOAD2A
#undef LOAD2B
#undef WRITE2
#undef COMP2

#pragma unroll
    for (int ri = 0; ri < 2; ++ri)
#pragma unroll
        for (int ci = 0; ci < 2; ++ci) {
            int n = x * 64 + wn * 32 + ci * 16 + l15;
#pragma unroll
            for (int r = 0; r < 4; ++r) {
                int row = row0 + wm * 32 + ri * 16 + g * 4 + r;
                if (row >= nrows) continue;
                Y[(size_t)(rbase + row) * D_DIM + n] = acc[ri][ci][r];
            }
        }
}

// ---------------- combine ----------------
__global__ __launch_bounds__(256) void combine_kernel(
    const float* __restrict__ Y, const int* __restrict__ pos,
    const float* __restrict__ wts, float* __restrict__ out)
{
    int t = blockIdx.x;
    int d = threadIdx.x * 4;
    int p0 = pos[2 * t], p1 = pos[2 * t + 1];
    float w0 = wts[2 * t], w1 = wts[2 * t + 1];
    float4 a = *(const float4*)(Y + (size_t)(N_SLOTS + t) * D_DIM + d);
    float4 b = *(const float4*)(Y + (size_t)p0 * D_DIM + d);
    float4 cc = *(const float4*)(Y + (size_t)p1 * D_DIM + d);
    float4 o;
    o.x = a.x + w0 * b.x + w1 * cc.x;
    o.y = a.y + w0 * b.y + w1 * cc.y;
    o.z = a.z + w0 * b.z + w1 * cc.z;
    o.w = a.w + w0 * b.w + w1 * cc.w;
    *(float4*)(out + (size_t)t * D_DIM + d) = o;
}

extern "C" void kernel_launch(void* const* d_in, const int* in_sizes, int n_in,
                              void* d_out, int out_size, void* d_ws, size_t ws_size,
                              hipStream_t stream) {
    const float* X    = (const float*)d_in[0];
    const float* Wr   = (const float*)d_in[1];
    const float* bias = (const float*)d_in[2];
    const float* Wg   = (const float*)d_in[3];
    const float* Wu   = (const float*)d_in[4];
    const float* Wd   = (const float*)d_in[5];
    const float* Wgs  = (const float*)d_in[6];
    const float* Wus  = (const float*)d_in[7];
    const float* Wds  = (const float*)d_in[8];
    float* out = (float*)d_out;

    char* ws = (char*)d_ws;
    int*   sel    = (int*)(ws + WS_SEL);
    float* wtsv   = (float*)(ws + WS_WTS);
    int*   bucket = (int*)(ws + WS_BUCKET);
    int*   counts = (int*)(ws + WS_COUNTS);
    int*   offs   = (int*)(ws + WS_OFFS);
    int*   pos    = (int*)(ws + WS_POS);
    u16*   Xb     = (u16*)(ws + WS_XB);
    u16*   H      = (u16*)(ws + WS_H);
    float* Y      = (float*)(ws + WS_Y);

    xrouter_kernel<<<256, 256, 0, stream>>>(X, Wr, bias, Xb, sel, wtsv);
    dispatch_kernel<<<1, 512, 0, stream>>>(sel, bucket, counts, offs, pos);

    proj1<<<1792, 256, 0, stream>>>(Xb, Wg, Wu, Wgs, Wus, H, bucket, counts, offs);
    proj2<<<2304, 256, 0, stream>>>(H, Wd, Wds, Y, counts, offs);
    combine_kernel<<<T_TOK, 256, 0, stream>>>(Y, pos, wtsv, out);
}

// Round 15
// 80.374 us; speedup vs baseline: 1.6383x; 1.0893x over previous
//
#include <hip/hip_runtime.h>
#include <hip/hip_bf16.h>
#include <math.h>

#define T_TOK   1024
#define D_DIM   1024
#define E_NUM   8
#define F_DIM   768
#define N_SLOTS 2048

typedef unsigned short u16;
typedef unsigned int   u32;
typedef __attribute__((ext_vector_type(8))) short bf16x8;
typedef __attribute__((ext_vector_type(4))) float f32x4;

// ---- workspace layout (byte offsets) ----
#define WS_SEL    0
#define WS_WTS    8192
#define WS_BUCKET 16384
#define WS_COUNTS 49152
#define WS_OFFS   49216
#define WS_POS    49280
#define WS_XB     65536                    // bf16[1024][1024]  2 MB
#define WS_H      (WS_XB + 2097152)        // bf16[3072][768]   4.7 MB
#define WS_Y      (WS_H + 4718592)         // f32 [3072][1024]  12.6 MB

__device__ __forceinline__ u16 f2bf(float x) {            // RNE
    u32 u = __float_as_uint(x);
    u += 0x7fffu + ((u >> 16) & 1u);
    return (u16)(u >> 16);
}
// pack 2 fp32 -> 2 bf16 (truncate) in one v_perm_b32: result = [hi.bf16 | lo.bf16]
#define PKBF(hi, lo) __builtin_amdgcn_perm(__float_as_uint(hi), __float_as_uint(lo), 0x07060302u)

// ---------------- xrouter: bf16-convert X row + router top-2 ----------------
__global__ __launch_bounds__(256) void xrouter_kernel(
    const float* __restrict__ X, const float* __restrict__ Wr,
    const float* __restrict__ bias, u16* __restrict__ Xb,
    int* __restrict__ sel, float* __restrict__ wts)
{
    int t = blockIdx.x * 4 + (threadIdx.x >> 6);
    int lane = threadIdx.x & 63;
    const float* xrow = X + (size_t)t * D_DIM;
    u16* brow = Xb + (size_t)t * D_DIM;
    float acc[E_NUM];
#pragma unroll
    for (int e = 0; e < E_NUM; ++e) acc[e] = 0.f;
#pragma unroll
    for (int q = 0; q < 4; ++q) {
        int d = q * 256 + lane * 4;
        float4 v = *(const float4*)(xrow + d);
        ushort4 o;
        o.x = f2bf(v.x); o.y = f2bf(v.y); o.z = f2bf(v.z); o.w = f2bf(v.w);
        *(ushort4*)(brow + d) = o;
        const float xv[4] = {v.x, v.y, v.z, v.w};
#pragma unroll
        for (int jj = 0; jj < 4; ++jj) {
            const float4* wr = (const float4*)(Wr + (size_t)(d + jj) * E_NUM);
            float4 w0 = wr[0], w1 = wr[1];
            acc[0] += xv[jj] * w0.x; acc[1] += xv[jj] * w0.y;
            acc[2] += xv[jj] * w0.z; acc[3] += xv[jj] * w0.w;
            acc[4] += xv[jj] * w1.x; acc[5] += xv[jj] * w1.y;
            acc[6] += xv[jj] * w1.z; acc[7] += xv[jj] * w1.w;
        }
    }
#pragma unroll
    for (int e = 0; e < E_NUM; ++e)
#pragma unroll
        for (int off = 32; off > 0; off >>= 1)
            acc[e] += __shfl_xor(acc[e], off);
    if (lane == 0) {
        float s[E_NUM], b[E_NUM];
#pragma unroll
        for (int e = 0; e < E_NUM; ++e) {
            s[e] = 1.f / (1.f + expf(-acc[e]));
            b[e] = s[e] + bias[e];
        }
        int i1 = 0; float b1 = b[0];
#pragma unroll
        for (int e = 1; e < E_NUM; ++e) if (b[e] > b1) { b1 = b[e]; i1 = e; }
        int i2 = -1; float b2 = -INFINITY;
#pragma unroll
        for (int e = 0; e < E_NUM; ++e) {
            if (e == i1) continue;
            if (b[e] > b2) { b2 = b[e]; i2 = e; }
        }
        float s1 = s[i1], s2 = s[i2];
        float denom = s1 + s2 + 1e-20f;
        sel[2 * t] = i1; sel[2 * t + 1] = i2;
        wts[2 * t] = s1 / denom; wts[2 * t + 1] = s2 / denom;
    }
}

// ---------------- dispatch ----------------
__global__ __launch_bounds__(512) void dispatch_kernel(
    const int* __restrict__ sel, int* __restrict__ bucket,
    int* __restrict__ counts, int* __restrict__ offs, int* __restrict__ pos)
{
    __shared__ int soffs[E_NUM + 1];
    int e = threadIdx.x >> 6;
    int lane = threadIdx.x & 63;
    int running = 0;
    for (int base = 0; base < N_SLOTS; base += 64) {
        int slot = base + lane;
        bool mine = (sel[slot] == e);
        unsigned long long mask = __ballot(mine);
        if (mine) {
            int rank = running + __popcll(mask & ((1ull << lane) - 1ull));
            bucket[e * T_TOK + rank] = slot;
        }
        running += __popcll(mask);
    }
    if (lane == 0) counts[e] = running;
    __syncthreads();
    if (threadIdx.x == 0) {
        int o = 0;
        for (int k = 0; k < E_NUM; ++k) { soffs[k] = o; offs[k] = o; o += counts[k]; }
        soffs[E_NUM] = o; offs[E_NUM] = o;
    }
    __syncthreads();
    int base_off = soffs[e];
    for (int r = lane; r < running; r += 64)
        pos[bucket[e * T_TOK + r]] = base_off + r;
}

// ================= proj1: H = silu(Xb@Wg) * (Xb@Wu), fp32 weights read directly =================
// BM=64, BN=128 virtual (gate 64 + up 64), BK=64, 16 K-steps, 1-deep dbuf (round-10 exact).
// LDS rows of 64 u16 (128B, 8 chunks), chunk swizzle phys = c ^ (row&7) (627K conflicts measured).
// grid 1792: cxcd=i&7, m=i>>3, y=m&15, phi=m>>4; panel=phi*8+cxcd (<108); unit=panel/12, x=panel%12
__global__ __launch_bounds__(256, 3) void proj1(
    const u16* __restrict__ Xb,
    const float* __restrict__ Wg, const float* __restrict__ Wu,
    const float* __restrict__ Wgs, const float* __restrict__ Wus,
    u16* __restrict__ H,
    const int* __restrict__ bucket, const int* __restrict__ counts, const int* __restrict__ offs)
{
    const int i = blockIdx.x;
    const int cxcd = i & 7, m = i >> 3;
    const int y = m & 15, phi = m >> 4;
    const int panel = phi * 8 + cxcd;
    if (panel >= 108) return;
    const int unit = panel / 12, x = panel - unit * 12;

    int nrows, rbase; const float *Bg, *Bu;
    if (unit < E_NUM) {
        nrows = counts[unit]; rbase = offs[unit];
        Bg = Wg + (size_t)unit * D_DIM * F_DIM;
        Bu = Wu + (size_t)unit * D_DIM * F_DIM;
    } else { nrows = T_TOK; rbase = N_SLOTS; Bg = Wgs; Bu = Wus; }
    const int row0 = y * 64;
    if (row0 >= nrows) return;

    // rows 0..63 = A, 64..127 = gate B, 128..191 = up B; each row 64 u16 (8 chunks)
    __shared__ u16 smem[2][192 * 64];

    const int t = threadIdx.x;
    const int wv = t >> 6, lane = t & 63, l15 = lane & 15, g = lane >> 4;
    const int wm = wv >> 1, wn = wv & 1;

    // ---- A staging: thread -> (row = t>>2, chunks c0 = t&3 and c0+4) ----
    const int ar = t >> 2, ac = t & 3;
    int grow = min(row0 + ar, nrows - 1);
    if (unit < E_NUM) grow = bucket[unit * T_TOK + grow] >> 1;
    const u16* srcA = Xb + (size_t)grow * D_DIM + ac * 8;
    const int wA0 = ar * 64 + ((ac     ^ (ar & 7)) * 8);
    const int wA1 = ar * 64 + (((ac+4) ^ (ar & 7)) * 8);

    // ---- B staging: thread -> vrow bn (0..127), k-half bh (32 k each) ----
    const int bn = (t & 63) | (((t >> 6) & 1) << 6);
    const int bh = t >> 7;
    const float* srcB = ((bn < 64) ? Bg : Bu) + (size_t)(bh * 32) * F_DIM + x * 64 + (bn & 63);
    int wB[4];
#pragma unroll
    for (int q = 0; q < 4; ++q)
        wB[q] = (64 + bn) * 64 + (((bh * 4 + q) ^ (bn & 7)) * 8);

    f32x4 accg[2][2], accu[2][2];
    const f32x4 z4 = {0.f, 0.f, 0.f, 0.f};
#pragma unroll
    for (int ri = 0; ri < 2; ++ri)
#pragma unroll
        for (int ci = 0; ci < 2; ++ci) { accg[ri][ci] = z4; accu[ri][ci] = z4; }

    uint4 pa0, pa1;
    float pb[32];
#define LOAD1(kt) do { \
    pa0 = *(const uint4*)(srcA + (kt)); \
    pa1 = *(const uint4*)(srcA + (kt) + 32); \
    const float* _bp = srcB + (size_t)(kt) * F_DIM; \
    _Pragma("unroll") \
    for (int ii = 0; ii < 32; ++ii) pb[ii] = _bp[(size_t)ii * F_DIM]; \
} while (0)
#define WRITE1(buf) do { \
    *(uint4*)&smem[buf][wA0] = pa0; \
    *(uint4*)&smem[buf][wA1] = pa1; \
    _Pragma("unroll") \
    for (int q = 0; q < 4; ++q) { \
        u32 pk[4]; \
        _Pragma("unroll") \
        for (int j = 0; j < 4; ++j) pk[j] = PKBF(pb[8*q + 2*j + 1], pb[8*q + 2*j]); \
        *(uint4*)&smem[buf][wB[q]] = *(const uint4*)pk; \
    } \
} while (0)
#define COMP1(buf) do { \
    const u16* _p = smem[buf]; \
    _Pragma("unroll") \
    for (int kk = 0; kk < 2; ++kk) { \
        const int ch = (((kk << 2) | g) ^ (l15 & 7)) * 8; \
        bf16x8 _a[2], _bg[2], _bu[2]; \
        _Pragma("unroll") \
        for (int ri = 0; ri < 2; ++ri) \
            _a[ri] = *(const bf16x8*)&_p[(wm * 32 + ri * 16 + l15) * 64 + ch]; \
        _Pragma("unroll") \
        for (int ci = 0; ci < 2; ++ci) { \
            _bg[ci] = *(const bf16x8*)&_p[(64  + wn * 32 + ci * 16 + l15) * 64 + ch]; \
            _bu[ci] = *(const bf16x8*)&_p[(128 + wn * 32 + ci * 16 + l15) * 64 + ch]; \
        } \
        _Pragma("unroll") \
        for (int ri = 0; ri < 2; ++ri) \
            _Pragma("unroll") \
            for (int ci = 0; ci < 2; ++ci) { \
                accg[ri][ci] = __builtin_amdgcn_mfma_f32_16x16x32_bf16(_a[ri], _bg[ci], accg[ri][ci], 0, 0, 0); \
                accu[ri][ci] = __builtin_amdgcn_mfma_f32_16x16x32_bf16(_a[ri], _bu[ci], accu[ri][ci], 0, 0, 0); \
            } \
    } \
} while (0)

    LOAD1(0);
    for (int tt = 0; tt < 16; ++tt) {
        WRITE1(tt & 1);
        if (tt + 1 < 16) LOAD1((tt + 1) * 64);
        __syncthreads();
        COMP1(tt & 1);
    }
#undef LOAD1
#undef WRITE1
#undef COMP1

    // epilogue: fused SiLU-GLU, write H bf16 (RNE)
#pragma unroll
    for (int ri = 0; ri < 2; ++ri)
#pragma unroll
        for (int ci = 0; ci < 2; ++ci) {
            int n = x * 64 + wn * 32 + ci * 16 + l15;
#pragma unroll
            for (int r = 0; r < 4; ++r) {
                int row = row0 + wm * 32 + ri * 16 + g * 4 + r;
                if (row >= nrows) continue;
                float gv = accg[ri][ci][r];
                float uv = accu[ri][ci][r];
                H[(size_t)(rbase + row) * F_DIM + n] =
                    f2bf(gv / (1.f + __expf(-gv)) * uv);
            }
        }
}

// ================= proj2: Y = H @ Wd, fp32 weights read directly (round-10 exact) =================
// BM=64, BN=64, BK=64, 12 K-steps, 1-deep dbuf. LDS rows 0..63 A, 64..127 B.
// grid 2304: cxcd=i&7, m=i>>3, y=m&15, phi=m>>4; panel=phi*8+cxcd (<144); unit=panel>>4, x=panel&15
__global__ __launch_bounds__(256, 3) void proj2(
    const u16* __restrict__ H,
    const float* __restrict__ Wd, const float* __restrict__ Wds,
    float* __restrict__ Y,
    const int* __restrict__ counts, const int* __restrict__ offs)
{
    const int i = blockIdx.x;
    const int cxcd = i & 7, m = i >> 3;
    const int y = m & 15, phi = m >> 4;
    const int panel = phi * 8 + cxcd;
    if (panel >= 144) return;
    const int unit = panel >> 4, x = panel & 15;

    int nrows, rbase; const float* Bm;
    if (unit < E_NUM) {
        nrows = counts[unit]; rbase = offs[unit];
        Bm = Wd + (size_t)unit * F_DIM * D_DIM;
    } else { nrows = T_TOK; rbase = N_SLOTS; Bm = Wds; }
    const int row0 = y * 64;
    if (row0 >= nrows) return;

    __shared__ u16 smem[2][128 * 64];

    const int t = threadIdx.x;
    const int wv = t >> 6, lane = t & 63, l15 = lane & 15, g = lane >> 4;
    const int wm = wv >> 1, wn = wv & 1;

    const int ar = t >> 2, ac = t & 3;
    const int grow = rbase + min(row0 + ar, nrows - 1);
    const u16* srcA = H + (size_t)grow * F_DIM + ac * 8;
    const int wA0 = ar * 64 + ((ac     ^ (ar & 7)) * 8);
    const int wA1 = ar * 64 + (((ac+4) ^ (ar & 7)) * 8);

    const int bn = t & 63;
    const int bq = t >> 6;
    const float* srcB = Bm + (size_t)(bq * 16) * D_DIM + x * 64 + bn;
    int wB[2];
#pragma unroll
    for (int q = 0; q < 2; ++q)
        wB[q] = (64 + bn) * 64 + (((bq * 2 + q) ^ (bn & 7)) * 8);

    f32x4 acc[2][2];
    const f32x4 z4 = {0.f, 0.f, 0.f, 0.f};
#pragma unroll
    for (int ri = 0; ri < 2; ++ri)
#pragma unroll
        for (int ci = 0; ci < 2; ++ci) acc[ri][ci] = z4;

    uint4 pa0, pa1;
    float pb[16];
#define LOAD2(kt) do { \
    pa0 = *(const uint4*)(srcA + (kt)); \
    pa1 = *(const uint4*)(srcA + (kt) + 32); \
    const float* _bp = srcB + (size_t)(kt) * D_DIM; \
    _Pragma("unroll") \
    for (int ii = 0; ii < 16; ++ii) pb[ii] = _bp[(size_t)ii * D_DIM]; \
} while (0)
#define WRITE2(buf) do { \
    *(uint4*)&smem[buf][wA0] = pa0; \
    *(uint4*)&smem[buf][wA1] = pa1; \
    _Pragma("unroll") \
    for (int q = 0; q < 2; ++q) { \
        u32 pk[4]; \
        _Pragma("unroll") \
        for (int j = 0; j < 4; ++j) pk[j] = PKBF(pb[8*q + 2*j + 1], pb[8*q + 2*j]); \
        *(uint4*)&smem[buf][wB[q]] = *(const uint4*)pk; \
    } \
} while (0)
#define COMP2(buf) do { \
    const u16* _p = smem[buf]; \
    _Pragma("unroll") \
    for (int kk = 0; kk < 2; ++kk) { \
        const int ch = (((kk << 2) | g) ^ (l15 & 7)) * 8; \
        bf16x8 _a[2], _b[2]; \
        _Pragma("unroll") \
        for (int ri = 0; ri < 2; ++ri) \
            _a[ri] = *(const bf16x8*)&_p[(wm * 32 + ri * 16 + l15) * 64 + ch]; \
        _Pragma("unroll") \
        for (int ci = 0; ci < 2; ++ci) \
            _b[ci] = *(const bf16x8*)&_p[(64 + wn * 32 + ci * 16 + l15) * 64 + ch]; \
        _Pragma("unroll") \
        for (int ri = 0; ri < 2; ++ri) \
            _Pragma("unroll") \
            for (int ci = 0; ci < 2; ++ci) \
                acc[ri][ci] = __builtin_amdgcn_mfma_f32_16x16x32_bf16(_a[ri], _b[ci], acc[ri][ci], 0, 0, 0); \
    } \
} while (0)

    LOAD2(0);
    for (int tt = 0; tt < 12; ++tt) {
        WRITE2(tt & 1);
        if (tt + 1 < 12) LOAD2((tt + 1) * 64);
        __syncthreads();
        COMP2(tt & 1);
    }
#undef LOAD2
#undef WRITE2
#undef COMP2

#pragma unroll
    for (int ri = 0; ri < 2; ++ri)
#pragma unroll
        for (int ci = 0; ci < 2; ++ci) {
            int n = x * 64 + wn * 32 + ci * 16 + l15;
#pragma unroll
            for (int r = 0; r < 4; ++r) {
                int row = row0 + wm * 32 + ri * 16 + g * 4 + r;
                if (row >= nrows) continue;
                Y[(size_t)(rbase + row) * D_DIM + n] = acc[ri][ci][r];
            }
        }
}

// ---------------- combine ----------------
__global__ __launch_bounds__(256) void combine_kernel(
    const float* __restrict__ Y, const int* __restrict__ pos,
    const float* __restrict__ wts, float* __restrict__ out)
{
    int t = blockIdx.x;
    int d = threadIdx.x * 4;
    int p0 = pos[2 * t], p1 = pos[2 * t + 1];
    float w0 = wts[2 * t], w1 = wts[2 * t + 1];
    float4 a = *(const float4*)(Y + (size_t)(N_SLOTS + t) * D_DIM + d);
    float4 b = *(const float4*)(Y + (size_t)p0 * D_DIM + d);
    float4 cc = *(const float4*)(Y + (size_t)p1 * D_DIM + d);
    float4 o;
    o.x = a.x + w0 * b.x + w1 * cc.x;
    o.y = a.y + w0 * b.y + w1 * cc.y;
    o.z = a.z + w0 * b.z + w1 * cc.z;
    o.w = a.w + w0 * b.w + w1 * cc.w;
    *(float4*)(out + (size_t)t * D_DIM + d) = o;
}

extern "C" void kernel_launch(void* const* d_in, const int* in_sizes, int n_in,
                              void* d_out, int out_size, void* d_ws, size_t ws_size,
                              hipStream_t stream) {
    const float* X    = (const float*)d_in[0];
    const float* Wr   = (const float*)d_in[1];
    const float* bias = (const float*)d_in[2];
    const float* Wg   = (const float*)d_in[3];
    const float* Wu   = (const float*)d_in[4];
    const float* Wd   = (const float*)d_in[5];
    const float* Wgs  = (const float*)d_in[6];
    const float* Wus  = (const float*)d_in[7];
    const float* Wds  = (const float*)d_in[8];
    float* out = (float*)d_out;

    char* ws = (char*)d_ws;
    int*   sel    = (int*)(ws + WS_SEL);
    float* wtsv   = (float*)(ws + WS_WTS);
    int*   bucket = (int*)(ws + WS_BUCKET);
    int*   counts = (int*)(ws + WS_COUNTS);
    int*   offs   = (int*)(ws + WS_OFFS);
    int*   pos    = (int*)(ws + WS_POS);
    u16*   Xb     = (u16*)(ws + WS_XB);
    u16*   H      = (u16*)(ws + WS_H);
    float* Y      = (float*)(ws + WS_Y);

    xrouter_kernel<<<256, 256, 0, stream>>>(X, Wr, bias, Xb, sel, wtsv);
    dispatch_kernel<<<1, 512, 0, stream>>>(sel, bucket, counts, offs, pos);

    proj1<<<1792, 256, 0, stream>>>(Xb, Wg, Wu, Wgs, Wus, H, bucket, counts, offs);
    proj2<<<2304, 256, 0, stream>>>(H, Wd, Wds, Y, counts, offs);
    combine_kernel<<<T_TOK, 256, 0, stream>>>(Y, pos, wtsv, out);
}